// Round 1
// baseline (558.396 us; speedup 1.0000x reference)
//
#include <hip/hip_runtime.h>
#include <hip/hip_bf16.h>

typedef short bf16x8 __attribute__((ext_vector_type(8)));
typedef float f32x4 __attribute__((ext_vector_type(4)));

struct __align__(8) us4 { unsigned short x, y, z, w; };

__device__ __forceinline__ unsigned short f2bfu(float f) {
  __hip_bfloat16 h = __float2bfloat16(f);
  unsigned short u; __builtin_memcpy(&u, &h, 2); return u;
}
__device__ __forceinline__ float bf2f(unsigned short u) {
  __hip_bfloat16 h; __builtin_memcpy(&h, &u, 2); return __bfloat162float(h);
}

// ---------------- LDS layout (bytes) ----------------
// Region XB [0, 17408):        x bf16 [64][136]           (live: whole kernel, used by QKV + aw-dot)
// Region C  [17408, 54272):    qk bf16 [64][264]  ->  p bf16 [4][64][72]  ->  att f32 [64][132]
// Region D  [54272, 72704):    v_t bf16 [128][72] ->  ctx bf16 [64][136]
// Region F  [72704, 79360):    awlog(256) aw(256) parts(4096) pooled(2048)
constexpr int XB_STR  = 136;
constexpr int C_OFF   = 17408;
constexpr int QK_STR  = 264;
constexpr int P_STR   = 72;
constexpr int ATT_STR = 132;
constexpr int D_OFF   = 54272;
constexpr int VT_STR  = 72;
constexpr int CTX_STR = 136;
constexpr int F_OFF   = 72704;
constexpr int SMEM_BYTES = 79360;

// ---- pre-kernel: convert W_in [384*128] and W_out [128*128] fp32 -> bf16 into d_ws ----
__global__ void wconv_kernel(const float* __restrict__ win, const float* __restrict__ wout,
                             unsigned short* __restrict__ dst) {
  int i = blockIdx.x * 256 + threadIdx.x;   // grid 256x256 = 65536 exact
  float v = (i < 49152) ? win[i] : wout[i - 49152];
  dst[i] = f2bfu(v);
}

__global__ __launch_bounds__(256, 2)
void fused_mol_kernel(const float* __restrict__ xg_all,
                      const unsigned short* __restrict__ wb,   // ws: W_in bf16 [384][128], W_out bf16 [128][128]
                      const float* __restrict__ b_in,
                      const float* __restrict__ b_out,
                      const float* __restrict__ W_pool,
                      const float* __restrict__ b_pool,
                      float* __restrict__ out)
{
  __shared__ __align__(16) char smem[SMEM_BYTES];
  const int tid  = threadIdx.x;
  const int wid  = tid >> 6;      // wave id 0..3  (== head id in attention phases)
  const int lane = tid & 63;
  const int lr   = lane & 15;
  const int lq   = lane >> 4;
  const int b    = blockIdx.x;

  unsigned short* xb  = (unsigned short*)(smem + 0);
  unsigned short* qk  = (unsigned short*)(smem + C_OFF);
  unsigned short* vt  = (unsigned short*)(smem + D_OFF);
  float* awlog  = (float*)(smem + F_OFF);
  float* aw     = (float*)(smem + F_OFF + 256);
  float* parts  = (float*)(smem + F_OFF + 512);
  float* pooled = (float*)(smem + F_OFF + 4608);

  // ================= Phase 0: load x -> xb (bf16) =================
  const float* xg = xg_all + (long)b * (64 * 128);
  #pragma unroll
  for (int i = 0; i < 8; ++i) {
    int f = i * 1024 + tid * 4;
    const float4 v = *(const float4*)(xg + f);
    int row = f >> 7, col = f & 127;
    us4 h; h.x = f2bfu(v.x); h.y = f2bfu(v.y); h.z = f2bfu(v.z); h.w = f2bfu(v.w);
    *(us4*)(xb + row * XB_STR + col) = h;
  }
  __syncthreads();

  // ================= Phase 1: QKV = x @ W_in^T + b_in =================
  // M=atom(64), N=e(384), K=d(128). Wave w owns e in [96w, 96w+96).
  {
    const unsigned short* win = wb;                 // [384][128] bf16
    bf16x8 Bf[6][4];
    #pragma unroll
    for (int nt = 0; nt < 6; ++nt) {
      int e = wid * 96 + nt * 16 + lr;
      #pragma unroll
      for (int k = 0; k < 4; ++k)
        Bf[nt][k] = *(const bf16x8*)(win + e * 128 + k * 32 + lq * 8);
    }
    #pragma unroll
    for (int mt = 0; mt < 4; ++mt) {
      bf16x8 Af[4];
      #pragma unroll
      for (int k = 0; k < 4; ++k)
        Af[k] = *(const bf16x8*)(xb + (mt * 16 + lr) * XB_STR + k * 32 + lq * 8);
      #pragma unroll
      for (int nt = 0; nt < 6; ++nt) {
        f32x4 acc = {0.f, 0.f, 0.f, 0.f};
        #pragma unroll
        for (int k = 0; k < 4; ++k)
          acc = __builtin_amdgcn_mfma_f32_16x16x32_bf16(Af[k], Bf[nt][k], acc, 0, 0, 0);
        int e = wid * 96 + nt * 16 + lr;
        float bias = b_in[e];
        int a0 = mt * 16 + lq * 4;
        if (e < 128) {                       // Q (fold in 1/sqrt(dh))
          const float sc = 0.17677669529663687f;
          #pragma unroll
          for (int r = 0; r < 4; ++r)
            qk[(a0 + r) * QK_STR + e] = f2bfu((acc[r] + bias) * sc);
        } else if (e < 256) {                // K
          #pragma unroll
          for (int r = 0; r < 4; ++r)
            qk[(a0 + r) * QK_STR + e] = f2bfu(acc[r] + bias);
        } else {                             // V -> transposed [dh][atom]
          int dh = e - 256;
          us4 h;
          h.x = f2bfu(acc[0] + bias); h.y = f2bfu(acc[1] + bias);
          h.z = f2bfu(acc[2] + bias); h.w = f2bfu(acc[3] + bias);
          *(us4*)(vt + dh * VT_STR + a0) = h;
        }
      }
    }
  }
  __syncthreads();

  // ================= Phase 2: scores^T = K @ Q^T (per wave head = wid) =================
  f32x4 sT[4][4];   // [mt = m tiles][nt = l tiles]
  {
    f32x4 zero = {0.f, 0.f, 0.f, 0.f};
    bf16x8 Af[4], Bf2[4];
    #pragma unroll
    for (int mt = 0; mt < 4; ++mt)
      Af[mt] = *(const bf16x8*)(qk + (mt * 16 + lr) * QK_STR + 128 + wid * 32 + lq * 8);
    #pragma unroll
    for (int nt = 0; nt < 4; ++nt)
      Bf2[nt] = *(const bf16x8*)(qk + (nt * 16 + lr) * QK_STR + wid * 32 + lq * 8);
    #pragma unroll
    for (int mt = 0; mt < 4; ++mt)
      #pragma unroll
      for (int nt = 0; nt < 4; ++nt)
        sT[mt][nt] = __builtin_amdgcn_mfma_f32_16x16x32_bf16(Af[mt], Bf2[nt], zero, 0, 0, 0);
  }
  __syncthreads();   // everyone done reading qk; region C becomes p

  // ---- softmax over m (column l is lane-local across {lr, lr+16, lr+32, lr+48}) ----
  unsigned short* pbuf = (unsigned short*)(smem + C_OFF) + wid * (64 * P_STR);
  #pragma unroll
  for (int nt = 0; nt < 4; ++nt) {
    float mx = -1e30f;
    #pragma unroll
    for (int mt = 0; mt < 4; ++mt)
      #pragma unroll
      for (int r = 0; r < 4; ++r) mx = fmaxf(mx, sT[mt][nt][r]);
    mx = fmaxf(mx, __shfl_xor(mx, 16));
    mx = fmaxf(mx, __shfl_xor(mx, 32));
    float ex[4][4]; float s = 0.f;
    #pragma unroll
    for (int mt = 0; mt < 4; ++mt)
      #pragma unroll
      for (int r = 0; r < 4; ++r) { ex[mt][r] = __expf(sT[mt][nt][r] - mx); s += ex[mt][r]; }
    s += __shfl_xor(s, 16);
    s += __shfl_xor(s, 32);
    float inv = 1.f / s;
    int l = nt * 16 + lr;
    #pragma unroll
    for (int mt = 0; mt < 4; ++mt) {
      us4 h;
      h.x = f2bfu(ex[mt][0] * inv); h.y = f2bfu(ex[mt][1] * inv);
      h.z = f2bfu(ex[mt][2] * inv); h.w = f2bfu(ex[mt][3] * inv);
      *(us4*)(pbuf + l * P_STR + mt * 16 + lq * 4) = h;
    }
  }

  // ================= Phase 3: ctx = P @ V (per wave head) =================
  f32x4 cacc[4][2];
  {
    #pragma unroll
    for (int mt = 0; mt < 4; ++mt)
      #pragma unroll
      for (int nt = 0; nt < 2; ++nt) cacc[mt][nt] = (f32x4){0.f, 0.f, 0.f, 0.f};
    #pragma unroll
    for (int kk = 0; kk < 2; ++kk) {
      bf16x8 Bf3[2];
      #pragma unroll
      for (int nt = 0; nt < 2; ++nt) {
        int dh = wid * 32 + nt * 16 + lr;
        Bf3[nt] = *(const bf16x8*)(vt + dh * VT_STR + kk * 32 + lq * 8);
      }
      #pragma unroll
      for (int mt = 0; mt < 4; ++mt) {
        bf16x8 Af = *(const bf16x8*)(pbuf + (mt * 16 + lr) * P_STR + kk * 32 + lq * 8);
        #pragma unroll
        for (int nt = 0; nt < 2; ++nt)
          cacc[mt][nt] = __builtin_amdgcn_mfma_f32_16x16x32_bf16(Af, Bf3[nt], cacc[mt][nt], 0, 0, 0);
      }
    }
  }
  __syncthreads();   // done reading v_t; region D becomes ctx
  unsigned short* ctx = (unsigned short*)(smem + D_OFF);
  #pragma unroll
  for (int mt = 0; mt < 4; ++mt)
    #pragma unroll
    for (int nt = 0; nt < 2; ++nt) {
      int dhg = wid * 32 + nt * 16 + lr;
      int l0 = mt * 16 + lq * 4;
      #pragma unroll
      for (int r = 0; r < 4; ++r)
        ctx[(l0 + r) * CTX_STR + dhg] = f2bfu(cacc[mt][nt][r]);
    }
  __syncthreads();

  // ================= Phase 4: attended = ctx @ W_out^T + b_out =================
  {
    const unsigned short* wout = wb + 49152;       // [128][128] bf16
    float* att = (float*)(smem + C_OFF);
    bf16x8 Bf4[2][4];
    #pragma unroll
    for (int nt = 0; nt < 2; ++nt) {
      int e = wid * 32 + nt * 16 + lr;
      #pragma unroll
      for (int k = 0; k < 4; ++k)
        Bf4[nt][k] = *(const bf16x8*)(wout + e * 128 + k * 32 + lq * 8);
    }
    #pragma unroll
    for (int mt = 0; mt < 4; ++mt) {
      bf16x8 Af[4];
      #pragma unroll
      for (int k = 0; k < 4; ++k)
        Af[k] = *(const bf16x8*)(ctx + (mt * 16 + lr) * CTX_STR + k * 32 + lq * 8);
      #pragma unroll
      for (int nt = 0; nt < 2; ++nt) {
        f32x4 acc = {0.f, 0.f, 0.f, 0.f};
        #pragma unroll
        for (int k = 0; k < 4; ++k)
          acc = __builtin_amdgcn_mfma_f32_16x16x32_bf16(Af[k], Bf4[nt][k], acc, 0, 0, 0);
        int e = wid * 32 + nt * 16 + lr;
        float bias = b_out[e];
        int l0 = mt * 16 + lq * 4;
        #pragma unroll
        for (int r = 0; r < 4; ++r)
          att[(l0 + r) * ATT_STR + e] = acc[r] + bias;
      }
    }
  }
  __syncthreads();

  // ================= Phase 5: pooling =================
  float* att = (float*)(smem + C_OFF);
  {  // aw logits: 4 threads per row l
    int l = tid >> 2, q = tid & 3;
    float s = 0.f;
    #pragma unroll
    for (int j = 0; j < 8; ++j) {
      int col = q * 32 + j * 4;
      float4 a = *(const float4*)(att + l * ATT_STR + col);
      us4 xh = *(const us4*)(xb + l * XB_STR + col);
      s += a.x * bf2f(xh.x) + a.y * bf2f(xh.y) + a.z * bf2f(xh.z) + a.w * bf2f(xh.w);
    }
    s += __shfl_xor(s, 1);
    s += __shfl_xor(s, 2);
    if (q == 0) awlog[l] = s;
  }
  __syncthreads();
  if (tid < 64) {
    float mx = -1e30f;
    for (int l = 0; l < 64; ++l) mx = fmaxf(mx, awlog[l]);
    float s = 0.f;
    for (int l = 0; l < 64; ++l) s += __expf(awlog[l] - mx);
    aw[tid] = __expf(awlog[tid] - mx) / s;
  }
  __syncthreads();
  {  // per-column stats, 2 threads per column
    int e = tid & 127, hf = tid >> 7;
    float mx = -1e30f, s = 0.f, s2 = 0.f, ws = 0.f;
    for (int i = 0; i < 32; ++i) {
      int l = hf * 32 + i;
      float a = att[l * ATT_STR + e];
      float w = aw[l];
      mx = fmaxf(mx, a); s += a; s2 += a * a; ws += a * w;
    }
    float4 pr; pr.x = mx; pr.y = s; pr.z = s2; pr.w = ws;
    *(float4*)(parts + (hf * 128 + e) * 4) = pr;
  }
  __syncthreads();
  if (tid < 128) {
    int e = tid;
    float4 p0 = *(const float4*)(parts + e * 4);
    float4 p1 = *(const float4*)(parts + (128 + e) * 4);
    float mx = fmaxf(p0.x, p1.x);
    float s = p0.y + p1.y, s2 = p0.z + p1.z, ws = p0.w + p1.w;
    float mean = s * (1.f / 64.f);
    float var = (s2 - s * mean) * (1.f / 63.f);
    var = fmaxf(var, 0.f);
    pooled[0 * 128 + e] = ws;          // weighted_mean
    pooled[1 * 128 + e] = mx;          // max
    pooled[2 * 128 + e] = mean;        // mean
    pooled[3 * 128 + e] = sqrtf(var);  // std (ddof=1)
  }
  __syncthreads();

  // ================= Phase 6: 4 small projections =================
  if (tid < 64) {
    int pp = tid >> 4;
    float acc = b_pool[tid];                       // [4][16] flat
    const float* wr = W_pool + tid * 128;          // [4][16][128] flat
    #pragma unroll 8
    for (int d = 0; d < 128; d += 4) {
      float4 w = *(const float4*)(wr + d);
      float4 pl = *(const float4*)(pooled + pp * 128 + d);
      acc += w.x * pl.x + w.y * pl.y + w.z * pl.z + w.w * pl.w;
    }
    out[(long)b * 64 + tid] = acc;
  }
}

extern "C" void kernel_launch(void* const* d_in, const int* in_sizes, int n_in,
                              void* d_out, int out_size, void* d_ws, size_t ws_size,
                              hipStream_t stream) {
  const float* x      = (const float*)d_in[0];
  // d_in[1] = batch_indices (unused: equal-length segments)
  const float* W_in   = (const float*)d_in[2];
  const float* b_in   = (const float*)d_in[3];
  const float* W_out  = (const float*)d_in[4];
  const float* b_out  = (const float*)d_in[5];
  const float* W_pool = (const float*)d_in[6];
  const float* b_pool = (const float*)d_in[7];
  unsigned short* wb = (unsigned short*)d_ws;      // 65536 bf16 = 128 KiB

  hipLaunchKernelGGL(wconv_kernel, dim3(256), dim3(256), 0, stream, W_in, W_out, wb);
  hipLaunchKernelGGL(fused_mol_kernel, dim3(8192), dim3(256), 0, stream,
                     x, wb, b_in, b_out, W_pool, b_pool, (float*)d_out);
}